// Round 1
// baseline (551.714 us; speedup 1.0000x reference)
//
#include <hip/hip_runtime.h>

// ---------------------------------------------------------------------------
// Sparse voxel encoder, fp32 dense pipeline.
// d_out = [out2 (24^3*64) | out1 (24^3*64) | out0 (48^3*32)]
// ---------------------------------------------------------------------------

constexpr int D0 = 96;

// ---------------- scatter: coords/feats -> dense grid + occupancy ----------
__global__ void scatter_kernel(const int* __restrict__ coords,
                               const float* __restrict__ feats,
                               float* __restrict__ x, float* __restrict__ occ,
                               int N) {
    int n = blockIdx.x * blockDim.x + threadIdx.x;
    if (n >= N) return;
    int i = coords[n * 3 + 0], j = coords[n * 3 + 1], k = coords[n * 3 + 2];
    int flat = (i * D0 + j) * D0 + k;
    const float4* f4 = reinterpret_cast<const float4*>(feats + (size_t)n * 8);
    float4 a = f4[0], b = f4[1];
    float* dst = x + (size_t)flat * 8;
    atomicAdd(dst + 0, a.x); atomicAdd(dst + 1, a.y);
    atomicAdd(dst + 2, a.z); atomicAdd(dst + 3, a.w);
    atomicAdd(dst + 4, b.x); atomicAdd(dst + 5, b.y);
    atomicAdd(dst + 6, b.z); atomicAdd(dst + 7, b.w);
    occ[flat] = 1.0f;
}

// ---------------- 2x2x2 max pool on occupancy ------------------------------
template <int GDO>
__global__ void pool_kernel(const float* __restrict__ occ_in,
                            float* __restrict__ occ_out) {
    int idx = blockIdx.x * blockDim.x + threadIdx.x;
    if (idx >= GDO * GDO * GDO) return;
    int x = idx % GDO, y = (idx / GDO) % GDO, z = idx / (GDO * GDO);
    constexpr int GDI = GDO * 2;
    float m = 0.f;
    #pragma unroll
    for (int dz = 0; dz < 2; dz++)
        #pragma unroll
        for (int dy = 0; dy < 2; dy++)
            #pragma unroll
            for (int dx = 0; dx < 2; dx++)
                m = fmaxf(m, occ_in[((z * 2 + dz) * GDI + y * 2 + dy) * GDI + x * 2 + dx]);
    occ_out[idx] = m;
}

// ---------------- 3x3x3 SAME conv, relu, occupancy mask --------------------
// Block: 256 threads, tile TX*TY*TZ voxels. Each thread: 1 voxel, CO_PER cout.
// LDS: halo tile as float4[CC/4][NV] (lane-sequential on read).
// Weights read via wave-uniform (scalar) loads from global (L2-cached).
template <int CIN, int COUT, int GD, int TX, int TY, int TZ, int CC, int COSPLIT>
__global__ __launch_bounds__(256) void conv3_kernel(
    const float* __restrict__ in, const float* __restrict__ W,
    const float* __restrict__ bias, const float* __restrict__ occ,
    float* __restrict__ out) {
    constexpr int HX = TX + 2, HY = TY + 2, HZ = TZ + 2;
    constexpr int NV = HX * HY * HZ;
    constexpr int VOX = TX * TY * TZ;
    constexpr int NG = 256 / VOX;
    constexpr int CO_PER = COUT / COSPLIT / NG;
    constexpr int NCH = CIN / CC;
    __shared__ float4 lds4[(CC / 4) * NV];

    const int t = threadIdx.x;
    constexpr int NBX = GD / TX;
    const int cs = blockIdx.x / NBX;
    const int bx = blockIdx.x % NBX;
    const int x0 = bx * TX, y0 = blockIdx.y * TY, z0 = blockIdx.z * TZ;
    const int v = t % VOX;
    const int g = t / VOX;
    const int tx = v % TX, ty = (v / TX) % TY, tz = v / (TX * TY);
    // wave-uniform by construction (VOX is 64 or 256) -> force into SGPR
    const int co_base = __builtin_amdgcn_readfirstlane((cs * NG + g) * CO_PER);

    float acc[CO_PER];
    #pragma unroll
    for (int i = 0; i < CO_PER; i++) acc[i] = 0.f;

    for (int ch = 0; ch < NCH; ++ch) {
        // ---- stage halo tile ----
        constexpr int T4 = NV * (CC / 4);
        for (int idx = t; idx < T4; idx += 256) {
            int c4 = idx % (CC / 4);
            int vox = idx / (CC / 4);
            int hx = vox % HX, hy = (vox / HX) % HY, hz = vox / (HX * HY);
            int gx = x0 + hx - 1, gy = y0 + hy - 1, gz = z0 + hz - 1;
            float4 val = make_float4(0.f, 0.f, 0.f, 0.f);
            if (gx >= 0 && gx < GD && gy >= 0 && gy < GD && gz >= 0 && gz < GD) {
                val = *reinterpret_cast<const float4*>(
                    in + (size_t)((gz * GD + gy) * GD + gx) * CIN + ch * CC + c4 * 4);
            }
            lds4[c4 * NV + vox] = val;
        }
        __syncthreads();
        // ---- compute ----
        #pragma unroll 1
        for (int tap = 0; tap < 27; ++tap) {
            int kx = tap % 3, ky = (tap / 3) % 3, kz = tap / 9;
            int vin = (tz + kz) * (HX * HY) + (ty + ky) * HX + (tx + kx);
            #pragma unroll
            for (int c4 = 0; c4 < CC / 4; ++c4) {
                float4 iv = lds4[c4 * NV + vin];
                const float* wp =
                    W + (size_t)(tap * CIN + ch * CC + c4 * 4) * COUT + co_base;
                #pragma unroll
                for (int o4 = 0; o4 < CO_PER / 4; ++o4) {
                    float4 w0 = *reinterpret_cast<const float4*>(wp + 0 * COUT + o4 * 4);
                    float4 w1 = *reinterpret_cast<const float4*>(wp + 1 * COUT + o4 * 4);
                    float4 w2 = *reinterpret_cast<const float4*>(wp + 2 * COUT + o4 * 4);
                    float4 w3 = *reinterpret_cast<const float4*>(wp + 3 * COUT + o4 * 4);
                    acc[o4 * 4 + 0] += iv.x * w0.x + iv.y * w1.x + iv.z * w2.x + iv.w * w3.x;
                    acc[o4 * 4 + 1] += iv.x * w0.y + iv.y * w1.y + iv.z * w2.y + iv.w * w3.y;
                    acc[o4 * 4 + 2] += iv.x * w0.z + iv.y * w1.z + iv.z * w2.z + iv.w * w3.z;
                    acc[o4 * 4 + 3] += iv.x * w0.w + iv.y * w1.w + iv.z * w2.w + iv.w * w3.w;
                }
            }
        }
        __syncthreads();
    }
    // ---- epilogue: bias, relu, occupancy mask ----
    int oz = z0 + tz, oy = y0 + ty, ox = x0 + tx;
    int oflat = (oz * GD + oy) * GD + ox;
    float o = occ[oflat];
    float* op = out + (size_t)oflat * COUT + co_base;
    #pragma unroll
    for (int o4 = 0; o4 < CO_PER / 4; o4++) {
        float4 r;
        r.x = fmaxf(acc[o4 * 4 + 0] + bias[co_base + o4 * 4 + 0], 0.f) * o;
        r.y = fmaxf(acc[o4 * 4 + 1] + bias[co_base + o4 * 4 + 1], 0.f) * o;
        r.z = fmaxf(acc[o4 * 4 + 2] + bias[co_base + o4 * 4 + 2], 0.f) * o;
        r.w = fmaxf(acc[o4 * 4 + 3] + bias[co_base + o4 * 4 + 3], 0.f) * o;
        *reinterpret_cast<float4*>(op + o4 * 4) = r;
    }
}

// ---------------- 2x2x2 stride-2 VALID conv, relu, occupancy mask ----------
// Block: 256 threads = 64 output voxels (4x4x4) x 4 cout groups.
template <int CIN, int COUT, int GDI, int CC>
__global__ __launch_bounds__(256) void convd_kernel(
    const float* __restrict__ in, const float* __restrict__ W,
    const float* __restrict__ bias, const float* __restrict__ occ,
    float* __restrict__ out) {
    constexpr int GDO = GDI / 2;
    constexpr int VOX = 64, NG = 4;
    constexpr int CO_PER = COUT / NG;
    constexpr int HX = 8, HY = 8, HZ = 8, NV = HX * HY * HZ;
    constexpr int NCH = CIN / CC;
    __shared__ float4 lds4[(CC / 4) * NV];

    const int t = threadIdx.x;
    const int x0 = blockIdx.x * 4, y0 = blockIdx.y * 4, z0 = blockIdx.z * 4;
    const int v = t % VOX;
    const int g = t / VOX;
    const int tx = v % 4, ty = (v / 4) % 4, tz = v / 16;
    const int co_base = __builtin_amdgcn_readfirstlane(g * CO_PER);

    float acc[CO_PER];
    #pragma unroll
    for (int i = 0; i < CO_PER; i++) acc[i] = 0.f;

    for (int ch = 0; ch < NCH; ++ch) {
        constexpr int T4 = NV * (CC / 4);
        for (int idx = t; idx < T4; idx += 256) {
            int c4 = idx % (CC / 4);
            int vox = idx / (CC / 4);
            int hx = vox % HX, hy = (vox / HX) % HY, hz = vox / (HX * HY);
            int gx = x0 * 2 + hx, gy = y0 * 2 + hy, gz = z0 * 2 + hz;
            lds4[c4 * NV + vox] = *reinterpret_cast<const float4*>(
                in + (size_t)((gz * GDI + gy) * GDI + gx) * CIN + ch * CC + c4 * 4);
        }
        __syncthreads();
        #pragma unroll 1
        for (int tap = 0; tap < 8; ++tap) {
            int kx = tap & 1, ky = (tap >> 1) & 1, kz = tap >> 2;
            int vin = (tz * 2 + kz) * (HX * HY) + (ty * 2 + ky) * HX + (tx * 2 + kx);
            #pragma unroll
            for (int c4 = 0; c4 < CC / 4; ++c4) {
                float4 iv = lds4[c4 * NV + vin];
                const float* wp =
                    W + (size_t)(tap * CIN + ch * CC + c4 * 4) * COUT + co_base;
                #pragma unroll
                for (int o4 = 0; o4 < CO_PER / 4; ++o4) {
                    float4 w0 = *reinterpret_cast<const float4*>(wp + 0 * COUT + o4 * 4);
                    float4 w1 = *reinterpret_cast<const float4*>(wp + 1 * COUT + o4 * 4);
                    float4 w2 = *reinterpret_cast<const float4*>(wp + 2 * COUT + o4 * 4);
                    float4 w3 = *reinterpret_cast<const float4*>(wp + 3 * COUT + o4 * 4);
                    acc[o4 * 4 + 0] += iv.x * w0.x + iv.y * w1.x + iv.z * w2.x + iv.w * w3.x;
                    acc[o4 * 4 + 1] += iv.x * w0.y + iv.y * w1.y + iv.z * w2.y + iv.w * w3.y;
                    acc[o4 * 4 + 2] += iv.x * w0.z + iv.y * w1.z + iv.z * w2.z + iv.w * w3.z;
                    acc[o4 * 4 + 3] += iv.x * w0.w + iv.y * w1.w + iv.z * w2.w + iv.w * w3.w;
                }
            }
        }
        __syncthreads();
    }
    int oz = z0 + tz, oy = y0 + ty, ox = x0 + tx;
    int oflat = (oz * GDO + oy) * GDO + ox;
    float o = occ[oflat];
    float* op = out + (size_t)oflat * COUT + co_base;
    #pragma unroll
    for (int o4 = 0; o4 < CO_PER / 4; o4++) {
        float4 r;
        r.x = fmaxf(acc[o4 * 4 + 0] + bias[co_base + o4 * 4 + 0], 0.f) * o;
        r.y = fmaxf(acc[o4 * 4 + 1] + bias[co_base + o4 * 4 + 1], 0.f) * o;
        r.z = fmaxf(acc[o4 * 4 + 2] + bias[co_base + o4 * 4 + 2], 0.f) * o;
        r.w = fmaxf(acc[o4 * 4 + 3] + bias[co_base + o4 * 4 + 3], 0.f) * o;
        *reinterpret_cast<float4*>(op + o4 * 4) = r;
    }
}

// ---------------------------------------------------------------------------
extern "C" void kernel_launch(void* const* d_in, const int* in_sizes, int n_in,
                              void* d_out, int out_size, void* d_ws, size_t ws_size,
                              hipStream_t stream) {
    const int* coords = (const int*)d_in[0];
    const float* feats = (const float*)d_in[1];
    const float* W0 = (const float*)d_in[2];
    const float* b0 = (const float*)d_in[3];
    const float* Wd0 = (const float*)d_in[4];
    const float* bd0 = (const float*)d_in[5];
    const float* W1 = (const float*)d_in[6];
    const float* b1 = (const float*)d_in[7];
    const float* Wd1 = (const float*)d_in[8];
    const float* bd1 = (const float*)d_in[9];
    const float* W2 = (const float*)d_in[10];
    const float* b2 = (const float*)d_in[11];
    const int N = in_sizes[0] / 3;

    // workspace layout (floats):
    //   x   @ 0          : 96^3*8  = 7,077,888   (dead after conv0; h1 reuses)
    //   occ @ 7,077,888  : 96^3    =   884,736
    //   h   @ 7,962,624  : 96^3*16 = 14,155,776
    //   occ0@ 22,118,400 : 48^3    =   110,592
    //   occ1@ 22,228,992 : 24^3    =    13,824
    float* ws = (float*)d_ws;
    float* x = ws;
    float* h1 = ws;  // reuse x region (3,538,944 floats needed, 7M available)
    float* occ = ws + 7077888;
    float* h = ws + 7962624;
    float* occ0 = ws + 22118400;
    float* occ1 = ws + 22228992;

    float* out = (float*)d_out;
    float* out2 = out;            // 24^3*64 = 884,736
    float* out1 = out + 884736;   // 24^3*64 = 884,736
    float* out0 = out + 1769472;  // 48^3*32 = 3,538,944

    // zero scatter targets (x + occ are contiguous)
    hipMemsetAsync(x, 0, (size_t)(7077888 + 884736) * sizeof(float), stream);

    scatter_kernel<<<(N + 255) / 256, 256, 0, stream>>>(coords, feats, x, occ, N);
    pool_kernel<48><<<(110592 + 255) / 256, 256, 0, stream>>>(occ, occ0);
    pool_kernel<24><<<(13824 + 255) / 256, 256, 0, stream>>>(occ0, occ1);

    // conv0: 96^3, 8->16, tile 8x8x4 (256 vox, 1 group of 16 cout)
    conv3_kernel<8, 16, 96, 8, 8, 4, 8, 1>
        <<<dim3(12, 12, 24), 256, 0, stream>>>(x, W0, b0, occ, h);
    // convd0: 96->48, 16->32
    convd_kernel<16, 32, 96, 16>
        <<<dim3(12, 12, 12), 256, 0, stream>>>(h, Wd0, bd0, occ0, out0);
    // conv1: 48^3, 32->32, tile 4x4x4 (64 vox x 4 groups of 8 cout)
    conv3_kernel<32, 32, 48, 4, 4, 4, 16, 1>
        <<<dim3(12, 12, 12), 256, 0, stream>>>(out0, W1, b1, occ0, h1);
    // convd1: 48->24, 32->64
    convd_kernel<32, 64, 48, 16>
        <<<dim3(6, 6, 6), 256, 0, stream>>>(h1, Wd1, bd1, occ1, out1);
    // conv2: 24^3, 64->64, tile 4x4x4, cosplit 2 (432 blocks)
    conv3_kernel<64, 64, 24, 4, 4, 4, 16, 2>
        <<<dim3(12, 6, 6), 256, 0, stream>>>(out1, W2, b2, occ1, out2);
}